// Round 6
// baseline (471.561 us; speedup 1.0000x reference)
//
#include <hip/hip_runtime.h>
#include <math.h>

#define NMESH 120
#define NKZ 61            // rfft half-spectrum along z
#define NTOT (120*120*120)
#define ALPHA_C 1.0

#define TILE 12           // mesh cells per tile per dim
#define NTPD 10           // tiles per dim
#define NTILE 1000
#define FP 17             // footprint per dim: TILE + 5
#define FPCELLS (FP*FP*FP)   // 4913
#define FPSTRIDE 4928        // padded tile stride

#define YCH 30            // y-lines per fft_z block

// ---- workspace layout (bytes) ----
// [0,24)      : 3 doubles: ek, sum(q), sum(q^2)     (zeroed by table_init)
// [64,115264) : float2 T[120*120] twiddle table
// [115264, +19712000)  : float buf[1000][4928] tile footprints (fully written by spread)
// [19827264, +7027200) : float2 C1[x][kz][y]
//    bin ints + sorted atoms ALIAS the C1 region (dead before fft_z writes C1)
// C2[kz][ky][x] ALIASES buf (buf dead after fft_z)
#define ACC_OFF     0
#define TAB_OFF     64
#define BUF_OFF     115264
#define C1_OFF      19827264
#define C2_OFF      115264
#define COUNTS_OFF  C1_OFF
#define OFFSETS_OFF (C1_OFF + 4096)
#define CURSOR_OFF  (C1_OFF + 8192)
#define SORTED_OFF  (C1_OFF + 12288)

// native LDS fp32 atomic (ds_add_f32) — plain atomicAdd compiles to a CAS loop
__device__ inline void lds_fadd(float* p, float v) { unsafeAtomicAdd(p, v); }

__device__ inline void inv3(const float* b, float* ib) {
    float a00=b[0],a01=b[1],a02=b[2],a10=b[3],a11=b[4],a12=b[5],a20=b[6],a21=b[7],a22=b[8];
    float c00 =  a11*a22 - a12*a21;
    float c01 = -(a10*a22 - a12*a20);
    float c02 =  a10*a21 - a11*a20;
    float c10 = -(a01*a22 - a02*a21);
    float c11 =  a00*a22 - a02*a20;
    float c12 = -(a00*a21 - a01*a20);
    float c20 =  a01*a12 - a02*a11;
    float c21 = -(a00*a12 - a02*a10);
    float c22 =  a00*a11 - a01*a10;
    float det = a00*c00 + a01*c01 + a02*c02;
    float inv = 1.0f/det;
    ib[0]=c00*inv; ib[1]=c10*inv; ib[2]=c20*inv;
    ib[3]=c01*inv; ib[4]=c11*inv; ib[5]=c21*inv;
    ib[6]=c02*inv; ib[7]=c12*inv; ib[8]=c22*inv;
}

__device__ inline void atom_pos(const float* __restrict__ box, float c0, float c1, float c2,
                                float* p) {
    float ib[9]; inv3(box, ib);
    #pragma unroll
    for (int d=0; d<3; ++d)
        p[d] = (c0*ib[0+d] + c1*ib[3+d] + c2*ib[6+d]) * 120.0f;
}

__device__ inline int wrap120(int i) { return ((i % 120) + 120) % 120; }

// order-6 Lagrange weights for one dim; x = pos - (floor(pos)+0.5)
__device__ inline void lag6(float x, float* w) {
    float df[6];
    #pragma unroll
    for (int k=0;k<6;++k) df[k] = x - ((float)k - 2.5f);
    w[0] = df[1]*df[2]*df[3]*df[4]*df[5] * (-1.0f/120.0f);
    w[1] = df[0]*df[2]*df[3]*df[4]*df[5] * ( 1.0f/24.0f);
    w[2] = df[0]*df[1]*df[3]*df[4]*df[5] * (-1.0f/12.0f);
    w[3] = df[0]*df[1]*df[2]*df[4]*df[5] * ( 1.0f/12.0f);
    w[4] = df[0]*df[1]*df[2]*df[3]*df[5] * (-1.0f/24.0f);
    w[5] = df[0]*df[1]*df[2]*df[3]*df[4] * ( 1.0f/120.0f);
}

// per-dim halo decomposition: cell c -> up to 2 (tile, local) pairs
__device__ inline int halo_pairs(int c, int* t, int* l) {
    int r = c % 12, ti = c / 12, n = 0;
    t[n] = ti;          l[n] = r + 2;  n++;
    if (r < 3)  { t[n] = (ti+9)%10; l[n] = r + 14; n++; }
    if (r >= 10){ t[n] = (ti+1)%10; l[n] = r - 10; n++; }
    return n;
}

// twiddle table + zero accumulators + zero tile counts
__global__ void table_init_kernel(float2* __restrict__ T,
                                  int* __restrict__ counts,
                                  double* __restrict__ acc) {
    int idx = blockIdx.x*blockDim.x + threadIdx.x;
    if (idx < 3) acc[idx] = 0.0;
    if (idx < NTILE) counts[idx] = 0;
    if (idx < 120*120) {
        int z = idx/120, k = idx - z*120;
        int m = (z*k) % 120;
        double ang = (2.0*M_PI/120.0) * (double)m;
        T[idx] = make_float2((float)cos(ang), (float)(-sin(ang)));
    }
}

// fused: tile histogram + sum(q) + sum(q^2)
__global__ void bin_count_q_kernel(const float* __restrict__ coords,
                                   const float* __restrict__ box,
                                   const float* __restrict__ charges,
                                   int* __restrict__ counts,
                                   double* __restrict__ acc, int n) {
    int i = blockIdx.x*blockDim.x + threadIdx.x;
    float v = 0.f, v2 = 0.f;
    if (i < n) {
        float p[3]; atom_pos(box, coords[3*i], coords[3*i+1], coords[3*i+2], p);
        int t[3];
        #pragma unroll
        for (int d=0; d<3; ++d) t[d] = wrap120((int)floorf(p[d])) / TILE;
        atomicAdd(&counts[(t[0]*NTPD + t[1])*NTPD + t[2]], 1);
        v = charges[i]; v2 = v*v;
    }
    #pragma unroll
    for (int o=32;o>0;o>>=1) { v += __shfl_down(v,o,64); v2 += __shfl_down(v2,o,64); }
    __shared__ float s1[4], s2[4];
    int lane = threadIdx.x & 63, w = threadIdx.x >> 6;
    if (lane==0) { s1[w]=v; s2[w]=v2; }
    __syncthreads();
    if (threadIdx.x==0) {
        for (int j=1;j<4;j++) { v += s1[j]; v2 += s2[j]; }
        atomicAdd(&acc[1], (double)v);
        atomicAdd(&acc[2], (double)v2);
    }
}

__global__ void scan_kernel(const int* __restrict__ counts,
                            int* __restrict__ offsets, int* __restrict__ cursor) {
    __shared__ int s[1024];
    int t = threadIdx.x;
    s[t] = (t < NTILE) ? counts[t] : 0;
    __syncthreads();
    for (int d=1; d<1024; d<<=1) {
        int v = (t >= d) ? s[t-d] : 0;
        __syncthreads();
        s[t] += v;
        __syncthreads();
    }
    int excl = (t==0) ? 0 : s[t-1];
    if (t < NTILE) { offsets[t] = excl; cursor[t] = excl; }
    if (t == NTILE-1) offsets[NTILE] = s[t];
}

__global__ void scatter_kernel(const float* __restrict__ coords,
                               const float* __restrict__ box,
                               const float* __restrict__ charges,
                               int* __restrict__ cursor,
                               float4* __restrict__ sorted, int n) {
    int i = blockIdx.x*blockDim.x + threadIdx.x;
    if (i >= n) return;
    float p[3]; atom_pos(box, coords[3*i], coords[3*i+1], coords[3*i+2], p);
    int t[3];
    #pragma unroll
    for (int d=0; d<3; ++d) t[d] = wrap120((int)floorf(p[d])) / TILE;
    int tile = (t[0]*NTPD + t[1])*NTPD + t[2];
    int pdst = atomicAdd(&cursor[tile], 1);
    sorted[pdst] = make_float4(p[0], p[1], p[2], charges[i]);
}

// one block per spatial tile. LDS-accumulate footprint (native ds_add_f32),
// flush with plain coalesced writes to a private per-tile buffer.
__global__ void __launch_bounds__(512, 8)
spread_tile_kernel(const float4* __restrict__ sorted,
                   const int* __restrict__ offsets,
                   float* __restrict__ buf) {
    int tile = blockIdx.x;
    int tx = tile / (NTPD*NTPD);
    int rem = tile - tx*NTPD*NTPD;
    int ty = rem / NTPD;
    int tz = rem - ty*NTPD;
    int bx = tx*TILE, by = ty*TILE, bz = tz*TILE;

    __shared__ float  accS[FPCELLS];
    __shared__ float4 atomS[256];

    int tid = threadIdx.x;
    for (int i = tid; i < FPCELLS; i += 512) accS[i] = 0.f;

    int beg = offsets[tile], end = offsets[tile+1];

    for (int start = beg; start < end; start += 256) {
        int cnt = min(256, end - start);
        if (tid < cnt) atomS[tid] = sorted[start + tid];
        __syncthreads();
        int pairs = cnt * 6;
        for (int p = tid; p < pairs; p += 512) {
            int ai = p / 6;
            int a  = p - ai*6;
            float4 s = atomS[ai];
            float fx = floorf(s.x);
            float wx[6]; lag6(s.x - (fx + 0.5f), wx);
            float wxa = ((a==0)?wx[0]:(a==1)?wx[1]:(a==2)?wx[2]:(a==3)?wx[3]:(a==4)?wx[4]:wx[5]) * s.w;
            int lx = wrap120((int)fx) - bx + a;          // [0,17)
            float fy = floorf(s.y);
            float wy[6]; lag6(s.y - (fy + 0.5f), wy);
            int ly = wrap120((int)fy) - by;              // [0,12)
            float fz = floorf(s.z);
            float wz[6]; lag6(s.z - (fz + 0.5f), wz);
            int lz = wrap120((int)fz) - bz;              // [0,12)
            int baseXY = (lx*FP + ly)*FP + lz;
            #pragma unroll
            for (int b=0;b<6;++b) {
                float wab = wxa * wy[b];
                int base = baseXY + b*FP;
                #pragma unroll
                for (int c=0;c<6;++c)
                    lds_fadd(&accS[base + c], wab * wz[c]);
            }
        }
        __syncthreads();
    }
    __syncthreads();

    float* dst = buf + (size_t)tile * FPSTRIDE;
    for (int i = tid; i < FPCELLS; i += 512) dst[i] = accS[i];
}

// stage 1: halo-gather + rfft along z. block = (x, 30-line y-chunk). out C1[x][kz][y].
__global__ void __launch_bounds__(256)
fft_z_kernel(const float* __restrict__ buf,
             const float2* __restrict__ T,
             float2* __restrict__ C1) {
    int x  = blockIdx.x >> 2;
    int y0 = (blockIdx.x & 3) * YCH;
    __shared__ float lds[YCH][121];

    // block-uniform x decomposition
    int txA[2], lxA[2];
    int nx = halo_pairs(x, txA, lxA);

    for (int i = threadIdx.x; i < YCH*120; i += 256) {
        int yl = i / 120, z = i - yl*120;
        int tyA[2], lyA[2]; int ny = halo_pairs(y0 + yl, tyA, lyA);
        int tzA[2], lzA[2]; int nz = halo_pairs(z, tzA, lzA);
        float s = 0.f;
        for (int ii=0; ii<nx; ++ii)
            for (int jj=0; jj<ny; ++jj)
                for (int kk=0; kk<nz; ++kk) {
                    int tile = (txA[ii]*NTPD + tyA[jj])*NTPD + tzA[kk];
                    int cell = (lxA[ii]*FP + lyA[jj])*FP + lzA[kk];
                    s += buf[(size_t)tile*FPSTRIDE + cell];
                }
        lds[yl][z] = s;
    }
    __syncthreads();
    for (int o = threadIdx.x; o < YCH*NKZ; o += 256) {
        int kz = o / YCH, yl = o - kz*YCH;
        float re = 0.f, im = 0.f;
        for (int z=0; z<120; ++z) {
            float v = lds[yl][z];
            float2 t = T[z*120 + kz];
            re = fmaf(v, t.x, re);
            im = fmaf(v, t.y, im);
        }
        C1[(x*NKZ + kz)*120 + y0 + yl] = make_float2(re, im);
    }
}

// stage 2: cfft along y. block = (8 consecutive x, kz). out C2[kz][ky][x].
__global__ void __launch_bounds__(256)
fft_y_kernel(const float2* __restrict__ C1,
             const float2* __restrict__ T,
             float2* __restrict__ C2) {
    int xc = blockIdx.x / NKZ;
    int kz = blockIdx.x - xc*NKZ;
    int x0 = xc * 8;
    __shared__ float2 lds[8][121];
    for (int i = threadIdx.x; i < 8*120; i += 256) {
        int xo = i / 120, y = i - xo*120;
        lds[xo][y] = C1[((x0+xo)*NKZ + kz)*120 + y];
    }
    __syncthreads();
    for (int o = threadIdx.x; o < 960; o += 256) {
        int ky = o >> 3, xo = o & 7;
        float re = 0.f, im = 0.f;
        for (int y=0; y<120; ++y) {
            float2 a = lds[xo][y];
            float2 t = T[y*120 + ky];
            re = fmaf(a.x, t.x, fmaf(-a.y, t.y, re));
            im = fmaf(a.x, t.y, fmaf( a.y, t.x, im));
        }
        C2[(kz*120 + ky)*120 + x0 + xo] = make_float2(re, im);
    }
}

// stage 3: cfft along x + G-weighted energy reduction. block = (kz, 8-ky chunk).
__global__ void __launch_bounds__(256)
fft_x_energy_kernel(const float2* __restrict__ C2,
                    const float2* __restrict__ T,
                    const float* __restrict__ box,
                    double* __restrict__ acc) {
    int kz  = blockIdx.x / 15;
    int ky0 = (blockIdx.x - kz*15) * 8;
    __shared__ float2 lds[8][121];
    const float2* src = C2 + (kz*120 + ky0)*120;
    for (int i = threadIdx.x; i < 960; i += 256) {
        int kyo = i / 120, x = i - kyo*120;
        lds[kyo][x] = src[i];
    }
    __syncthreads();
    float ib[9]; inv3(box, ib);
    const float TWOPI = 6.283185307179586f;
    float wzf = (kz==0 || kz==60) ? 1.0f : 2.0f;
    float contrib = 0.f;
    for (int o = threadIdx.x; o < 960; o += 256) {
        int kyo = o / 120, kx = o - kyo*120;
        int ky = ky0 + kyo;
        float re = 0.f, im = 0.f;
        for (int x=0; x<120; ++x) {
            float2 a = lds[kyo][x];
            float2 t = T[x*120 + kx];
            re = fmaf(a.x, t.x, fmaf(-a.y, t.y, re));
            im = fmaf(a.x, t.y, fmaf( a.y, t.x, im));
        }
        if (!(kx==0 && ky==0 && kz==0)) {
            float mx = (kx < 60) ? (float)kx : (float)(kx - 120);
            float my = (ky < 60) ? (float)ky : (float)(ky - 120);
            float mz = (float)kz;
            float k0 = TWOPI*(mx*ib[0] + my*ib[1] + mz*ib[2]);
            float k1 = TWOPI*(mx*ib[3] + my*ib[4] + mz*ib[5]);
            float k2 = TWOPI*(mx*ib[6] + my*ib[7] + mz*ib[8]);
            float ksq = k0*k0 + k1*k1 + k2*k2;
            float G = 12.566370614359172f * __expf(-0.5f*(float)(ALPHA_C*ALPHA_C)*ksq) / ksq;
            contrib += wzf * G * (re*re + im*im);
        }
    }
    #pragma unroll
    for (int o=32;o>0;o>>=1) contrib += __shfl_down(contrib,o,64);
    __shared__ float sm[4];
    int lane = threadIdx.x & 63, w = threadIdx.x >> 6;
    if (lane==0) sm[w] = contrib;
    __syncthreads();
    if (threadIdx.x==0)
        atomicAdd(&acc[0], (double)(sm[0]+sm[1]+sm[2]+sm[3]));
}

__global__ void finalize_kernel(const double* __restrict__ acc,
                                const float* __restrict__ box,
                                float* __restrict__ out) {
    double ek = acc[0], sq = acc[1], sq2 = acc[2];
    double a00=box[0],a01=box[1],a02=box[2],a10=box[3],a11=box[4],a12=box[5],a20=box[6],a21=box[7],a22=box[8];
    double det = a00*(a11*a22-a12*a21) - a01*(a10*a22-a12*a20) + a02*(a10*a21-a11*a20);
    double vol = fabs(det);
    double E = ek/(2.0*vol)
             - 0.5*sqrt(2.0/M_PI)/ALPHA_C * sq2
             - M_PI*ALPHA_C*ALPHA_C * sq*sq / vol;
    out[0] = (float)E;
}

extern "C" void kernel_launch(void* const* d_in, const int* in_sizes, int n_in,
                              void* d_out, int out_size, void* d_ws, size_t ws_size,
                              hipStream_t stream) {
    const float* coords  = (const float*)d_in[0];
    const float* box     = (const float*)d_in[1];
    const float* charges = (const float*)d_in[2];
    int n = in_sizes[0] / 3;

    char* ws = (char*)d_ws;
    double* acc   = (double*)(ws + ACC_OFF);
    float2* T     = (float2*)(ws + TAB_OFF);
    float*  buf   = (float*) (ws + BUF_OFF);
    float2* C1    = (float2*)(ws + C1_OFF);
    float2* C2    = (float2*)(ws + C2_OFF);
    int* counts   = (int*)(ws + COUNTS_OFF);
    int* offsets  = (int*)(ws + OFFSETS_OFF);
    int* cursor   = (int*)(ws + CURSOR_OFF);
    float4* sorted= (float4*)(ws + SORTED_OFF);

    int gA = (n + 255)/256;
    table_init_kernel<<<(14400+255)/256, 256, 0, stream>>>(T, counts, acc);
    bin_count_q_kernel<<<gA, 256, 0, stream>>>(coords, box, charges, counts, acc, n);
    scan_kernel<<<1, 1024, 0, stream>>>(counts, offsets, cursor);
    scatter_kernel<<<gA, 256, 0, stream>>>(coords, box, charges, cursor, sorted, n);
    spread_tile_kernel<<<NTILE, 512, 0, stream>>>(sorted, offsets, buf);
    fft_z_kernel<<<120*4, 256, 0, stream>>>(buf, T, C1);
    fft_y_kernel<<<15*NKZ, 256, 0, stream>>>(C1, T, C2);
    fft_x_energy_kernel<<<NKZ*15, 256, 0, stream>>>(C2, T, box, acc);
    finalize_kernel<<<1, 1, 0, stream>>>(acc, box, (float*)d_out);
}

// Round 7
// 254.991 us; speedup vs baseline: 1.8493x; 1.8493x over previous
//
#include <hip/hip_runtime.h>
#include <math.h>

#define NMESH 120
#define NKZ 61            // rfft half-spectrum along z
#define NTOT (120*120*120)
#define ALPHA_C 1.0

#define TILE 12           // mesh cells per tile per dim
#define NTPD 10           // tiles per dim
#define NTILE 1000
#define FP 17             // footprint per dim: TILE + 5
#define FPCELLS (FP*FP*FP)   // 4913
#define FPSTRIDE 4928        // padded tile stride

#define YCH 30            // y-lines per fft_z block

// ---- workspace layout (bytes) ----
// [0,24)      : 3 doubles: ek, sum(q), sum(q^2)     (zeroed by init)
// [115264, +19712000)  : float buf[1000][4928] tile footprints (fully written by spread)
// [19827264, +7027200) : float2 C1[x][kz][y]
//    bin ints + sorted atoms ALIAS the C1 region (dead before fft_z writes C1)
// C2[kz][ky][x] ALIASES buf (buf dead after fft_z)
#define ACC_OFF     0
#define BUF_OFF     115264
#define C1_OFF      19827264
#define C2_OFF      115264
#define COUNTS_OFF  C1_OFF
#define OFFSETS_OFF (C1_OFF + 4096)
#define CURSOR_OFF  (C1_OFF + 8192)
#define SORTED_OFF  (C1_OFF + 12288)

__device__ inline void inv3(const float* b, float* ib) {
    float a00=b[0],a01=b[1],a02=b[2],a10=b[3],a11=b[4],a12=b[5],a20=b[6],a21=b[7],a22=b[8];
    float c00 =  a11*a22 - a12*a21;
    float c01 = -(a10*a22 - a12*a20);
    float c02 =  a10*a21 - a11*a20;
    float c10 = -(a01*a22 - a02*a21);
    float c11 =  a00*a22 - a02*a20;
    float c12 = -(a00*a21 - a01*a20);
    float c20 =  a01*a12 - a02*a11;
    float c21 = -(a00*a12 - a02*a10);
    float c22 =  a00*a11 - a01*a10;
    float det = a00*c00 + a01*c01 + a02*c02;
    float inv = 1.0f/det;
    ib[0]=c00*inv; ib[1]=c10*inv; ib[2]=c20*inv;
    ib[3]=c01*inv; ib[4]=c11*inv; ib[5]=c21*inv;
    ib[6]=c02*inv; ib[7]=c12*inv; ib[8]=c22*inv;
}

__device__ inline void atom_pos(const float* __restrict__ box, float c0, float c1, float c2,
                                float* p) {
    float ib[9]; inv3(box, ib);
    #pragma unroll
    for (int d=0; d<3; ++d)
        p[d] = (c0*ib[0+d] + c1*ib[3+d] + c2*ib[6+d]) * 120.0f;
}

__device__ inline int wrap120(int i) { return ((i % 120) + 120) % 120; }

// order-6 Lagrange weights for one dim; x = pos - (floor(pos)+0.5)
__device__ inline void lag6(float x, float* w) {
    float df[6];
    #pragma unroll
    for (int k=0;k<6;++k) df[k] = x - ((float)k - 2.5f);
    w[0] = df[1]*df[2]*df[3]*df[4]*df[5] * (-1.0f/120.0f);
    w[1] = df[0]*df[2]*df[3]*df[4]*df[5] * ( 1.0f/24.0f);
    w[2] = df[0]*df[1]*df[3]*df[4]*df[5] * (-1.0f/12.0f);
    w[3] = df[0]*df[1]*df[2]*df[4]*df[5] * ( 1.0f/12.0f);
    w[4] = df[0]*df[1]*df[2]*df[3]*df[5] * (-1.0f/24.0f);
    w[5] = df[0]*df[1]*df[2]*df[3]*df[4] * ( 1.0f/120.0f);
}

// per-dim halo decomposition: cell c -> up to 2 (tile, local) pairs
__device__ inline int halo_pairs(int c, int* t, int* l) {
    int r = c % 12, ti = c / 12, n = 0;
    t[n] = ti;          l[n] = r + 2;  n++;
    if (r < 3)  { t[n] = (ti+9)%10; l[n] = r + 14; n++; }
    if (r >= 10){ t[n] = (ti+1)%10; l[n] = r - 10; n++; }
    return n;
}

__global__ void init_kernel(int* __restrict__ counts, double* __restrict__ acc) {
    int idx = threadIdx.x;
    if (idx < 3) acc[idx] = 0.0;
    for (int i = idx; i < NTILE; i += 1024) counts[i] = 0;
}

// fused: tile histogram + sum(q) + sum(q^2)
__global__ void bin_count_q_kernel(const float* __restrict__ coords,
                                   const float* __restrict__ box,
                                   const float* __restrict__ charges,
                                   int* __restrict__ counts,
                                   double* __restrict__ acc, int n) {
    int i = blockIdx.x*blockDim.x + threadIdx.x;
    float v = 0.f, v2 = 0.f;
    if (i < n) {
        float p[3]; atom_pos(box, coords[3*i], coords[3*i+1], coords[3*i+2], p);
        int t[3];
        #pragma unroll
        for (int d=0; d<3; ++d) t[d] = wrap120((int)floorf(p[d])) / TILE;
        atomicAdd(&counts[(t[0]*NTPD + t[1])*NTPD + t[2]], 1);
        v = charges[i]; v2 = v*v;
    }
    #pragma unroll
    for (int o=32;o>0;o>>=1) { v += __shfl_down(v,o,64); v2 += __shfl_down(v2,o,64); }
    __shared__ float s1[4], s2[4];
    int lane = threadIdx.x & 63, w = threadIdx.x >> 6;
    if (lane==0) { s1[w]=v; s2[w]=v2; }
    __syncthreads();
    if (threadIdx.x==0) {
        for (int j=1;j<4;j++) { v += s1[j]; v2 += s2[j]; }
        atomicAdd(&acc[1], (double)v);
        atomicAdd(&acc[2], (double)v2);
    }
}

__global__ void scan_kernel(const int* __restrict__ counts,
                            int* __restrict__ offsets, int* __restrict__ cursor) {
    __shared__ int s[1024];
    int t = threadIdx.x;
    s[t] = (t < NTILE) ? counts[t] : 0;
    __syncthreads();
    for (int d=1; d<1024; d<<=1) {
        int v = (t >= d) ? s[t-d] : 0;
        __syncthreads();
        s[t] += v;
        __syncthreads();
    }
    int excl = (t==0) ? 0 : s[t-1];
    if (t < NTILE) { offsets[t] = excl; cursor[t] = excl; }
    if (t == NTILE-1) offsets[NTILE] = s[t];
}

__global__ void scatter_kernel(const float* __restrict__ coords,
                               const float* __restrict__ box,
                               const float* __restrict__ charges,
                               int* __restrict__ cursor,
                               float4* __restrict__ sorted, int n) {
    int i = blockIdx.x*blockDim.x + threadIdx.x;
    if (i >= n) return;
    float p[3]; atom_pos(box, coords[3*i], coords[3*i+1], coords[3*i+2], p);
    int t[3];
    #pragma unroll
    for (int d=0; d<3; ++d) t[d] = wrap120((int)floorf(p[d])) / TILE;
    int tile = (t[0]*NTPD + t[1])*NTPD + t[2];
    int pdst = atomicAdd(&cursor[tile], 1);
    sorted[pdst] = make_float4(p[0], p[1], p[2], charges[i]);
}

// ONE WAVE per tile. Atoms processed serially; lane=(a,b) footprint slice does
// 6 PLAIN LDS read-add-write ops on exclusively-owned cells. No atomics.
// Single-wave in-order LDS ops make cross-atom RMW safe without barriers.
__global__ void __launch_bounds__(64)
spread_tile_kernel(const float4* __restrict__ sorted,
                   const int* __restrict__ offsets,
                   float* __restrict__ buf) {
    int tile = blockIdx.x;
    int tx = tile / (NTPD*NTPD);
    int rem = tile - tx*NTPD*NTPD;
    int ty = rem / NTPD;
    int tz = rem - ty*NTPD;
    int bx = tx*TILE, by = ty*TILE, bz = tz*TILE;

    __shared__ float accS[FPCELLS];
    __shared__ float W[64][18];     // [atom][wx*q(6), wy(6), wz(6)]
    __shared__ int   baseS[64];

    int tid = threadIdx.x;
    for (int i = tid; i < FPCELLS; i += 64) accS[i] = 0.f;

    int a = tid / 6, b = tid - a*6;          // lane slice, active for tid<36
    int laneoff = a*(FP*FP) + b*FP;

    int beg = offsets[tile], end = offsets[tile+1];

    for (int start = beg; start < end; start += 64) {
        int cnt = min(64, end - start);
        if (tid < cnt) {
            float4 s = sorted[start + tid];
            float fx = floorf(s.x);
            float wx[6]; lag6(s.x - (fx + 0.5f), wx);
            float fy = floorf(s.y);
            float wy[6]; lag6(s.y - (fy + 0.5f), wy);
            float fz = floorf(s.z);
            float wz[6]; lag6(s.z - (fz + 0.5f), wz);
            int lx = wrap120((int)fx) - bx;  // [0,12)
            int ly = wrap120((int)fy) - by;
            int lz = wrap120((int)fz) - bz;
            baseS[tid] = (lx*FP + ly)*FP + lz;
            #pragma unroll
            for (int k=0;k<6;++k) {
                W[tid][k]    = wx[k]*s.w;
                W[tid][6+k]  = wy[k];
                W[tid][12+k] = wz[k];
            }
        }
        __syncthreads();   // single wave: near-free; guards LDS visibility
        if (tid < 36) {
            for (int j = 0; j < cnt; ++j) {
                float w2 = W[j][a] * W[j][6+b];
                int ad = baseS[j] + laneoff;
                #pragma unroll
                for (int c=0;c<6;++c)
                    accS[ad + c] += w2 * W[j][12+c];
            }
        }
        __syncthreads();
    }

    for (int i = tid; i < FPCELLS; i += 64)
        buf[(size_t)tile * FPSTRIDE + i] = accS[i];
}

// stage 1: halo-gather + rfft along z via twiddle recurrence. out C1[x][kz][y].
__global__ void __launch_bounds__(256)
fft_z_kernel(const float* __restrict__ buf,
             float2* __restrict__ C1) {
    int x  = blockIdx.x >> 2;
    int y0 = (blockIdx.x & 3) * YCH;
    __shared__ float lds[YCH][121];

    int txA[2], lxA[2];
    int nx = halo_pairs(x, txA, lxA);

    for (int i = threadIdx.x; i < YCH*120; i += 256) {
        int yl = i / 120, z = i - yl*120;
        int tyA[2], lyA[2]; int ny = halo_pairs(y0 + yl, tyA, lyA);
        int tzA[2], lzA[2]; int nz = halo_pairs(z, tzA, lzA);
        float s = 0.f;
        for (int ii=0; ii<nx; ++ii)
            for (int jj=0; jj<ny; ++jj)
                for (int kk=0; kk<nz; ++kk) {
                    int tile = (txA[ii]*NTPD + tyA[jj])*NTPD + tzA[kk];
                    int cell = (lxA[ii]*FP + lyA[jj])*FP + lzA[kk];
                    s += buf[(size_t)tile*FPSTRIDE + cell];
                }
        lds[yl][z] = s;
    }
    __syncthreads();
    for (int o = threadIdx.x; o < YCH*NKZ; o += 256) {
        int kz = o / YCH, yl = o - kz*YCH;
        double th = -2.0*M_PI*(double)kz/120.0;
        double sd, cd; sincos(th, &sd, &cd);
        float w1r = (float)cd, w1i = (float)sd;
        float wr = 1.f, wi = 0.f;
        float re = 0.f, im = 0.f;
        for (int z=0; z<120; ++z) {
            float v = lds[yl][z];
            re = fmaf(v, wr, re);
            im = fmaf(v, wi, im);
            float nr = wr*w1r - wi*w1i;
            float ni = wr*w1i + wi*w1r;
            wr = nr; wi = ni;
        }
        C1[(x*NKZ + kz)*120 + y0 + yl] = make_float2(re, im);
    }
}

// stage 2: cfft along y via recurrence. block = (8 consecutive x, kz). out C2[kz][ky][x].
__global__ void __launch_bounds__(256)
fft_y_kernel(const float2* __restrict__ C1,
             float2* __restrict__ C2) {
    int xc = blockIdx.x / NKZ;
    int kz = blockIdx.x - xc*NKZ;
    int x0 = xc * 8;
    __shared__ float2 lds[8][121];
    for (int i = threadIdx.x; i < 8*120; i += 256) {
        int xo = i / 120, y = i - xo*120;
        lds[xo][y] = C1[((x0+xo)*NKZ + kz)*120 + y];
    }
    __syncthreads();
    for (int o = threadIdx.x; o < 960; o += 256) {
        int ky = o >> 3, xo = o & 7;
        double th = -2.0*M_PI*(double)ky/120.0;
        double sd, cd; sincos(th, &sd, &cd);
        float w1r = (float)cd, w1i = (float)sd;
        float wr = 1.f, wi = 0.f;
        float re = 0.f, im = 0.f;
        for (int y=0; y<120; ++y) {
            float2 aa = lds[xo][y];
            re = fmaf(aa.x, wr, fmaf(-aa.y, wi, re));
            im = fmaf(aa.x, wi, fmaf( aa.y, wr, im));
            float nr = wr*w1r - wi*w1i;
            float ni = wr*w1i + wi*w1r;
            wr = nr; wi = ni;
        }
        C2[(kz*120 + ky)*120 + x0 + xo] = make_float2(re, im);
    }
}

// stage 3: cfft along x (recurrence) + G-weighted energy reduction.
__global__ void __launch_bounds__(256)
fft_x_energy_kernel(const float2* __restrict__ C2,
                    const float* __restrict__ box,
                    double* __restrict__ acc) {
    int kz  = blockIdx.x / 15;
    int ky0 = (blockIdx.x - kz*15) * 8;
    __shared__ float2 lds[8][121];
    const float2* src = C2 + (kz*120 + ky0)*120;
    for (int i = threadIdx.x; i < 960; i += 256) {
        int kyo = i / 120, x = i - kyo*120;
        lds[kyo][x] = src[i];
    }
    __syncthreads();
    float ib[9]; inv3(box, ib);
    const float TWOPI = 6.283185307179586f;
    float wzf = (kz==0 || kz==60) ? 1.0f : 2.0f;
    float contrib = 0.f;
    for (int o = threadIdx.x; o < 960; o += 256) {
        int kyo = o / 120, kx = o - kyo*120;
        int ky = ky0 + kyo;
        double th = -2.0*M_PI*(double)kx/120.0;
        double sd, cd; sincos(th, &sd, &cd);
        float w1r = (float)cd, w1i = (float)sd;
        float wr = 1.f, wi = 0.f;
        float re = 0.f, im = 0.f;
        for (int x=0; x<120; ++x) {
            float2 aa = lds[kyo][x];
            re = fmaf(aa.x, wr, fmaf(-aa.y, wi, re));
            im = fmaf(aa.x, wi, fmaf( aa.y, wr, im));
            float nr = wr*w1r - wi*w1i;
            float ni = wr*w1i + wi*w1r;
            wr = nr; wi = ni;
        }
        if (!(kx==0 && ky==0 && kz==0)) {
            float mx = (kx < 60) ? (float)kx : (float)(kx - 120);
            float my = (ky < 60) ? (float)ky : (float)(ky - 120);
            float mz = (float)kz;
            float k0 = TWOPI*(mx*ib[0] + my*ib[1] + mz*ib[2]);
            float k1 = TWOPI*(mx*ib[3] + my*ib[4] + mz*ib[5]);
            float k2 = TWOPI*(mx*ib[6] + my*ib[7] + mz*ib[8]);
            float ksq = k0*k0 + k1*k1 + k2*k2;
            float G = 12.566370614359172f * __expf(-0.5f*(float)(ALPHA_C*ALPHA_C)*ksq) / ksq;
            contrib += wzf * G * (re*re + im*im);
        }
    }
    #pragma unroll
    for (int o=32;o>0;o>>=1) contrib += __shfl_down(contrib,o,64);
    __shared__ float sm[4];
    int lane = threadIdx.x & 63, w = threadIdx.x >> 6;
    if (lane==0) sm[w] = contrib;
    __syncthreads();
    if (threadIdx.x==0)
        atomicAdd(&acc[0], (double)(sm[0]+sm[1]+sm[2]+sm[3]));
}

__global__ void finalize_kernel(const double* __restrict__ acc,
                                const float* __restrict__ box,
                                float* __restrict__ out) {
    double ek = acc[0], sq = acc[1], sq2 = acc[2];
    double a00=box[0],a01=box[1],a02=box[2],a10=box[3],a11=box[4],a12=box[5],a20=box[6],a21=box[7],a22=box[8];
    double det = a00*(a11*a22-a12*a21) - a01*(a10*a22-a12*a20) + a02*(a10*a21-a11*a20);
    double vol = fabs(det);
    double E = ek/(2.0*vol)
             - 0.5*sqrt(2.0/M_PI)/ALPHA_C * sq2
             - M_PI*ALPHA_C*ALPHA_C * sq*sq / vol;
    out[0] = (float)E;
}

extern "C" void kernel_launch(void* const* d_in, const int* in_sizes, int n_in,
                              void* d_out, int out_size, void* d_ws, size_t ws_size,
                              hipStream_t stream) {
    const float* coords  = (const float*)d_in[0];
    const float* box     = (const float*)d_in[1];
    const float* charges = (const float*)d_in[2];
    int n = in_sizes[0] / 3;

    char* ws = (char*)d_ws;
    double* acc   = (double*)(ws + ACC_OFF);
    float*  buf   = (float*) (ws + BUF_OFF);
    float2* C1    = (float2*)(ws + C1_OFF);
    float2* C2    = (float2*)(ws + C2_OFF);
    int* counts   = (int*)(ws + COUNTS_OFF);
    int* offsets  = (int*)(ws + OFFSETS_OFF);
    int* cursor   = (int*)(ws + CURSOR_OFF);
    float4* sorted= (float4*)(ws + SORTED_OFF);

    int gA = (n + 255)/256;
    init_kernel<<<1, 1024, 0, stream>>>(counts, acc);
    bin_count_q_kernel<<<gA, 256, 0, stream>>>(coords, box, charges, counts, acc, n);
    scan_kernel<<<1, 1024, 0, stream>>>(counts, offsets, cursor);
    scatter_kernel<<<gA, 256, 0, stream>>>(coords, box, charges, cursor, sorted, n);
    spread_tile_kernel<<<NTILE, 64, 0, stream>>>(sorted, offsets, buf);
    fft_z_kernel<<<120*4, 256, 0, stream>>>(buf, C1);
    fft_y_kernel<<<15*NKZ, 256, 0, stream>>>(C1, C2);
    fft_x_energy_kernel<<<NKZ*15, 256, 0, stream>>>(C2, box, acc);
    finalize_kernel<<<1, 1, 0, stream>>>(acc, box, (float*)d_out);
}

// Round 8
// 237.561 us; speedup vs baseline: 1.9850x; 1.0734x over previous
//
#include <hip/hip_runtime.h>
#include <math.h>

#define NMESH 120
#define NKZ 61            // rfft half-spectrum along z
#define NTOT (120*120*120)
#define ALPHA_C 1.0

#define TILE 12           // mesh cells per tile per dim
#define NTPD 10           // tiles per dim
#define NTILE 1000
#define FP 17             // footprint per dim: TILE + 5
#define FPCELLS (FP*FP*FP)   // 4913
#define FPSTRIDE 4928        // padded tile stride

#define YCH 12            // y-lines per fft_z block (1200 blocks)
#define XCH 4             // x per fft_y block / ky per fft_x block

// ---- workspace layout (bytes) ----
// [0,24)      : 3 doubles: ek, sum(q), sum(q^2)     (zeroed by init)
// [115264, +19712000)  : float buf[1000][4928] tile footprints
// [19827264, +7027200) : float2 C1[x][kz][y]
//    bin ints + sorted atoms ALIAS the C1 region (dead before fft_z writes C1)
// C2[kz][ky][x] ALIASES buf (buf dead after fft_z)
#define ACC_OFF     0
#define BUF_OFF     115264
#define C1_OFF      19827264
#define C2_OFF      115264
#define COUNTS_OFF  C1_OFF
#define OFFSETS_OFF (C1_OFF + 4096)
#define CURSOR_OFF  (C1_OFF + 8192)
#define SORTED_OFF  (C1_OFF + 12288)

__device__ inline void inv3(const float* b, float* ib) {
    float a00=b[0],a01=b[1],a02=b[2],a10=b[3],a11=b[4],a12=b[5],a20=b[6],a21=b[7],a22=b[8];
    float c00 =  a11*a22 - a12*a21;
    float c01 = -(a10*a22 - a12*a20);
    float c02 =  a10*a21 - a11*a20;
    float c10 = -(a01*a22 - a02*a21);
    float c11 =  a00*a22 - a02*a20;
    float c12 = -(a00*a21 - a01*a20);
    float c20 =  a01*a12 - a02*a11;
    float c21 = -(a00*a12 - a02*a10);
    float c22 =  a00*a11 - a01*a10;
    float det = a00*c00 + a01*c01 + a02*c02;
    float inv = 1.0f/det;
    ib[0]=c00*inv; ib[1]=c10*inv; ib[2]=c20*inv;
    ib[3]=c01*inv; ib[4]=c11*inv; ib[5]=c21*inv;
    ib[6]=c02*inv; ib[7]=c12*inv; ib[8]=c22*inv;
}

__device__ inline void atom_pos(const float* __restrict__ box, float c0, float c1, float c2,
                                float* p) {
    float ib[9]; inv3(box, ib);
    #pragma unroll
    for (int d=0; d<3; ++d)
        p[d] = (c0*ib[0+d] + c1*ib[3+d] + c2*ib[6+d]) * 120.0f;
}

__device__ inline int wrap120(int i) { return ((i % 120) + 120) % 120; }

// order-6 Lagrange weights; x = pos - (floor(pos)+0.5)
__device__ inline void lag6(float x, float* w) {
    float df[6];
    #pragma unroll
    for (int k=0;k<6;++k) df[k] = x - ((float)k - 2.5f);
    w[0] = df[1]*df[2]*df[3]*df[4]*df[5] * (-1.0f/120.0f);
    w[1] = df[0]*df[2]*df[3]*df[4]*df[5] * ( 1.0f/24.0f);
    w[2] = df[0]*df[1]*df[3]*df[4]*df[5] * (-1.0f/12.0f);
    w[3] = df[0]*df[1]*df[2]*df[4]*df[5] * ( 1.0f/12.0f);
    w[4] = df[0]*df[1]*df[2]*df[3]*df[5] * (-1.0f/24.0f);
    w[5] = df[0]*df[1]*df[2]*df[3]*df[4] * ( 1.0f/120.0f);
}

// per-dim halo decomposition: cell c -> up to 2 (tile, local) pairs
__device__ inline int halo_pairs(int c, int* t, int* l) {
    int r = c % 12, ti = c / 12, n = 0;
    t[n] = ti;          l[n] = r + 2;  n++;
    if (r < 3)  { t[n] = (ti+9)%10; l[n] = r + 14; n++; }
    if (r >= 10){ t[n] = (ti+1)%10; l[n] = r - 10; n++; }
    return n;
}

// 4-strand twiddle init for frequency k: u_j = W^j, s = W^4, W = e^{-2pi i k/120}
struct Strand4 { float ur[4], ui[4], sr, si; };
__device__ inline Strand4 strand_init(int k) {
    Strand4 st;
    double th = -2.0*M_PI*(double)k/120.0;
    double sd, cd; sincos(th, &sd, &cd);
    float w1r = (float)cd, w1i = (float)sd;
    st.ur[0]=1.f;  st.ui[0]=0.f;
    st.ur[1]=w1r;  st.ui[1]=w1i;
    st.ur[2]=w1r*w1r - w1i*w1i;        st.ui[2]=2.f*w1r*w1i;
    st.ur[3]=st.ur[2]*w1r - st.ui[2]*w1i;  st.ui[3]=st.ur[2]*w1i + st.ui[2]*w1r;
    st.sr = st.ur[2]*st.ur[2] - st.ui[2]*st.ui[2];
    st.si = 2.f*st.ur[2]*st.ui[2];
    return st;
}

__global__ void init_kernel(int* __restrict__ counts, double* __restrict__ acc) {
    int idx = threadIdx.x;
    if (idx < 3) acc[idx] = 0.0;
    for (int i = idx; i < NTILE; i += 1024) counts[i] = 0;
}

// fused: tile histogram + sum(q) + sum(q^2)
__global__ void bin_count_q_kernel(const float* __restrict__ coords,
                                   const float* __restrict__ box,
                                   const float* __restrict__ charges,
                                   int* __restrict__ counts,
                                   double* __restrict__ acc, int n) {
    int i = blockIdx.x*blockDim.x + threadIdx.x;
    float v = 0.f, v2 = 0.f;
    if (i < n) {
        float p[3]; atom_pos(box, coords[3*i], coords[3*i+1], coords[3*i+2], p);
        int t[3];
        #pragma unroll
        for (int d=0; d<3; ++d) t[d] = wrap120((int)floorf(p[d])) / TILE;
        atomicAdd(&counts[(t[0]*NTPD + t[1])*NTPD + t[2]], 1);
        v = charges[i]; v2 = v*v;
    }
    #pragma unroll
    for (int o=32;o>0;o>>=1) { v += __shfl_down(v,o,64); v2 += __shfl_down(v2,o,64); }
    __shared__ float s1[4], s2[4];
    int lane = threadIdx.x & 63, w = threadIdx.x >> 6;
    if (lane==0) { s1[w]=v; s2[w]=v2; }
    __syncthreads();
    if (threadIdx.x==0) {
        for (int j=1;j<4;j++) { v += s1[j]; v2 += s2[j]; }
        atomicAdd(&acc[1], (double)v);
        atomicAdd(&acc[2], (double)v2);
    }
}

__global__ void scan_kernel(const int* __restrict__ counts,
                            int* __restrict__ offsets, int* __restrict__ cursor) {
    __shared__ int s[1024];
    int t = threadIdx.x;
    s[t] = (t < NTILE) ? counts[t] : 0;
    __syncthreads();
    for (int d=1; d<1024; d<<=1) {
        int v = (t >= d) ? s[t-d] : 0;
        __syncthreads();
        s[t] += v;
        __syncthreads();
    }
    int excl = (t==0) ? 0 : s[t-1];
    if (t < NTILE) { offsets[t] = excl; cursor[t] = excl; }
    if (t == NTILE-1) offsets[NTILE] = s[t];
}

__global__ void scatter_kernel(const float* __restrict__ coords,
                               const float* __restrict__ box,
                               const float* __restrict__ charges,
                               int* __restrict__ cursor,
                               float4* __restrict__ sorted, int n) {
    int i = blockIdx.x*blockDim.x + threadIdx.x;
    if (i >= n) return;
    float p[3]; atom_pos(box, coords[3*i], coords[3*i+1], coords[3*i+2], p);
    int t[3];
    #pragma unroll
    for (int d=0; d<3; ++d) t[d] = wrap120((int)floorf(p[d])) / TILE;
    int tile = (t[0]*NTPD + t[1])*NTPD + t[2];
    int pdst = atomicAdd(&cursor[tile], 1);
    sorted[pdst] = make_float4(p[0], p[1], p[2], charges[i]);
}

// ONE WAVE per tile; lane=(a,b) slice does 6 PLAIN LDS RMW ops on owned cells.
__global__ void __launch_bounds__(64)
spread_tile_kernel(const float4* __restrict__ sorted,
                   const int* __restrict__ offsets,
                   float* __restrict__ buf) {
    int tile = blockIdx.x;
    int tx = tile / (NTPD*NTPD);
    int rem = tile - tx*NTPD*NTPD;
    int ty = rem / NTPD;
    int tz = rem - ty*NTPD;
    int bx = tx*TILE, by = ty*TILE, bz = tz*TILE;

    __shared__ float accS[FPCELLS];
    __shared__ float W[64][18];
    __shared__ int   baseS[64];

    int tid = threadIdx.x;
    for (int i = tid; i < FPCELLS; i += 64) accS[i] = 0.f;

    int a = tid / 6, b = tid - a*6;
    int laneoff = a*(FP*FP) + b*FP;

    int beg = offsets[tile], end = offsets[tile+1];

    for (int start = beg; start < end; start += 64) {
        int cnt = min(64, end - start);
        if (tid < cnt) {
            float4 s = sorted[start + tid];
            float fx = floorf(s.x);
            float wx[6]; lag6(s.x - (fx + 0.5f), wx);
            float fy = floorf(s.y);
            float wy[6]; lag6(s.y - (fy + 0.5f), wy);
            float fz = floorf(s.z);
            float wz[6]; lag6(s.z - (fz + 0.5f), wz);
            int lx = wrap120((int)fx) - bx;
            int ly = wrap120((int)fy) - by;
            int lz = wrap120((int)fz) - bz;
            baseS[tid] = (lx*FP + ly)*FP + lz;
            #pragma unroll
            for (int k=0;k<6;++k) {
                W[tid][k]    = wx[k]*s.w;
                W[tid][6+k]  = wy[k];
                W[tid][12+k] = wz[k];
            }
        }
        __syncthreads();
        if (tid < 36) {
            for (int j = 0; j < cnt; ++j) {
                float w2 = W[j][a] * W[j][6+b];
                int ad = baseS[j] + laneoff;
                #pragma unroll
                for (int c=0;c<6;++c)
                    accS[ad + c] += w2 * W[j][12+c];
            }
        }
        __syncthreads();
    }

    for (int i = tid; i < FPCELLS; i += 64)
        buf[(size_t)tile * FPSTRIDE + i] = accS[i];
}

// stage 1: halo-gather + rfft along z, 4-strand recurrence. out C1[x][kz][y].
__global__ void __launch_bounds__(256)
fft_z_kernel(const float* __restrict__ buf,
             float2* __restrict__ C1) {
    int x  = blockIdx.x / 10;
    int y0 = (blockIdx.x - (blockIdx.x/10)*10) * YCH;
    __shared__ float lds[YCH][121];

    int txA[2], lxA[2];
    int nx = halo_pairs(x, txA, lxA);

    for (int i = threadIdx.x; i < YCH*120; i += 256) {
        int yl = i / 120, z = i - yl*120;
        int tyA[2], lyA[2]; int ny = halo_pairs(y0 + yl, tyA, lyA);
        int tzA[2], lzA[2]; int nz = halo_pairs(z, tzA, lzA);
        float s = 0.f;
        for (int ii=0; ii<nx; ++ii)
            for (int jj=0; jj<ny; ++jj)
                for (int kk=0; kk<nz; ++kk) {
                    int tile = (txA[ii]*NTPD + tyA[jj])*NTPD + tzA[kk];
                    int cell = (lxA[ii]*FP + lyA[jj])*FP + lzA[kk];
                    s += buf[(size_t)tile*FPSTRIDE + cell];
                }
        lds[yl][z] = s;
    }
    __syncthreads();
    for (int o = threadIdx.x; o < YCH*NKZ; o += 256) {
        int kz = o / YCH, yl = o - kz*YCH;
        Strand4 st = strand_init(kz);
        float rr[4] = {0.f,0.f,0.f,0.f}, ii2[4] = {0.f,0.f,0.f,0.f};
        for (int m=0; m<30; ++m) {
            #pragma unroll
            for (int j=0;j<4;++j) {
                float v = lds[yl][4*m+j];
                rr[j]  = fmaf(v, st.ur[j], rr[j]);
                ii2[j] = fmaf(v, st.ui[j], ii2[j]);
                float nr = st.ur[j]*st.sr - st.ui[j]*st.si;
                float ni = st.ur[j]*st.si + st.ui[j]*st.sr;
                st.ur[j] = nr; st.ui[j] = ni;
            }
        }
        float re = (rr[0]+rr[1]) + (rr[2]+rr[3]);
        float im = (ii2[0]+ii2[1]) + (ii2[2]+ii2[3]);
        C1[(x*NKZ + kz)*120 + y0 + yl] = make_float2(re, im);
    }
}

// stage 2: cfft along y, 4-strand. block = (4 consecutive x, kz). out C2[kz][ky][x].
__global__ void __launch_bounds__(256)
fft_y_kernel(const float2* __restrict__ C1,
             float2* __restrict__ C2) {
    int xc = blockIdx.x / NKZ;
    int kz = blockIdx.x - xc*NKZ;
    int x0 = xc * XCH;
    __shared__ float2 lds[XCH][121];
    for (int i = threadIdx.x; i < XCH*120; i += 256) {
        int xo = i / 120, y = i - xo*120;
        lds[xo][y] = C1[((x0+xo)*NKZ + kz)*120 + y];
    }
    __syncthreads();
    for (int o = threadIdx.x; o < XCH*120; o += 256) {
        int ky = o >> 2, xo = o & 3;
        Strand4 st = strand_init(ky);
        float rr[4] = {0.f,0.f,0.f,0.f}, ii2[4] = {0.f,0.f,0.f,0.f};
        for (int m=0; m<30; ++m) {
            #pragma unroll
            for (int j=0;j<4;++j) {
                float2 aa = lds[xo][4*m+j];
                rr[j]  = fmaf(aa.x, st.ur[j], fmaf(-aa.y, st.ui[j], rr[j]));
                ii2[j] = fmaf(aa.x, st.ui[j], fmaf( aa.y, st.ur[j], ii2[j]));
                float nr = st.ur[j]*st.sr - st.ui[j]*st.si;
                float ni = st.ur[j]*st.si + st.ui[j]*st.sr;
                st.ur[j] = nr; st.ui[j] = ni;
            }
        }
        float re = (rr[0]+rr[1]) + (rr[2]+rr[3]);
        float im = (ii2[0]+ii2[1]) + (ii2[2]+ii2[3]);
        C2[(kz*120 + ky)*120 + x0 + xo] = make_float2(re, im);
    }
}

// stage 3: cfft along x (4-strand) + G-weighted energy reduction.
// block = (kz, 4-ky chunk). grid = 61*30.
__global__ void __launch_bounds__(256)
fft_x_energy_kernel(const float2* __restrict__ C2,
                    const float* __restrict__ box,
                    double* __restrict__ acc) {
    int kyc = blockIdx.x / NKZ;
    int kz  = blockIdx.x - kyc*NKZ;
    int ky0 = kyc * XCH;
    __shared__ float2 lds[XCH][121];
    const float2* src = C2 + (kz*120 + ky0)*120;
    for (int i = threadIdx.x; i < XCH*120; i += 256) {
        int kyo = i / 120, x = i - kyo*120;
        lds[kyo][x] = src[i];
    }
    __syncthreads();
    float ib[9]; inv3(box, ib);
    const float TWOPI = 6.283185307179586f;
    float wzf = (kz==0 || kz==60) ? 1.0f : 2.0f;
    float contrib = 0.f;
    for (int o = threadIdx.x; o < XCH*120; o += 256) {
        int kyo = o / 120, kx = o - kyo*120;
        int ky = ky0 + kyo;
        Strand4 st = strand_init(kx);
        float rr[4] = {0.f,0.f,0.f,0.f}, ii2[4] = {0.f,0.f,0.f,0.f};
        for (int m=0; m<30; ++m) {
            #pragma unroll
            for (int j=0;j<4;++j) {
                float2 aa = lds[kyo][4*m+j];
                rr[j]  = fmaf(aa.x, st.ur[j], fmaf(-aa.y, st.ui[j], rr[j]));
                ii2[j] = fmaf(aa.x, st.ui[j], fmaf( aa.y, st.ur[j], ii2[j]));
                float nr = st.ur[j]*st.sr - st.ui[j]*st.si;
                float ni = st.ur[j]*st.si + st.ui[j]*st.sr;
                st.ur[j] = nr; st.ui[j] = ni;
            }
        }
        float re = (rr[0]+rr[1]) + (rr[2]+rr[3]);
        float im = (ii2[0]+ii2[1]) + (ii2[2]+ii2[3]);
        if (!(kx==0 && ky==0 && kz==0)) {
            float mx = (kx < 60) ? (float)kx : (float)(kx - 120);
            float my = (ky < 60) ? (float)ky : (float)(ky - 120);
            float mz = (float)kz;
            float k0 = TWOPI*(mx*ib[0] + my*ib[1] + mz*ib[2]);
            float k1 = TWOPI*(mx*ib[3] + my*ib[4] + mz*ib[5]);
            float k2 = TWOPI*(mx*ib[6] + my*ib[7] + mz*ib[8]);
            float ksq = k0*k0 + k1*k1 + k2*k2;
            float G = 12.566370614359172f * __expf(-0.5f*(float)(ALPHA_C*ALPHA_C)*ksq) / ksq;
            contrib += wzf * G * (re*re + im*im);
        }
    }
    #pragma unroll
    for (int o=32;o>0;o>>=1) contrib += __shfl_down(contrib,o,64);
    __shared__ float sm[4];
    int lane = threadIdx.x & 63, w = threadIdx.x >> 6;
    if (lane==0) sm[w] = contrib;
    __syncthreads();
    if (threadIdx.x==0)
        atomicAdd(&acc[0], (double)(sm[0]+sm[1]+sm[2]+sm[3]));
}

__global__ void finalize_kernel(const double* __restrict__ acc,
                                const float* __restrict__ box,
                                float* __restrict__ out) {
    double ek = acc[0], sq = acc[1], sq2 = acc[2];
    double a00=box[0],a01=box[1],a02=box[2],a10=box[3],a11=box[4],a12=box[5],a20=box[6],a21=box[7],a22=box[8];
    double det = a00*(a11*a22-a12*a21) - a01*(a10*a22-a12*a20) + a02*(a10*a21-a11*a20);
    double vol = fabs(det);
    double E = ek/(2.0*vol)
             - 0.5*sqrt(2.0/M_PI)/ALPHA_C * sq2
             - M_PI*ALPHA_C*ALPHA_C * sq*sq / vol;
    out[0] = (float)E;
}

extern "C" void kernel_launch(void* const* d_in, const int* in_sizes, int n_in,
                              void* d_out, int out_size, void* d_ws, size_t ws_size,
                              hipStream_t stream) {
    const float* coords  = (const float*)d_in[0];
    const float* box     = (const float*)d_in[1];
    const float* charges = (const float*)d_in[2];
    int n = in_sizes[0] / 3;

    char* ws = (char*)d_ws;
    double* acc   = (double*)(ws + ACC_OFF);
    float*  buf   = (float*) (ws + BUF_OFF);
    float2* C1    = (float2*)(ws + C1_OFF);
    float2* C2    = (float2*)(ws + C2_OFF);
    int* counts   = (int*)(ws + COUNTS_OFF);
    int* offsets  = (int*)(ws + OFFSETS_OFF);
    int* cursor   = (int*)(ws + CURSOR_OFF);
    float4* sorted= (float4*)(ws + SORTED_OFF);

    int gA = (n + 255)/256;
    init_kernel<<<1, 1024, 0, stream>>>(counts, acc);
    bin_count_q_kernel<<<gA, 256, 0, stream>>>(coords, box, charges, counts, acc, n);
    scan_kernel<<<1, 1024, 0, stream>>>(counts, offsets, cursor);
    scatter_kernel<<<gA, 256, 0, stream>>>(coords, box, charges, cursor, sorted, n);
    spread_tile_kernel<<<NTILE, 64, 0, stream>>>(sorted, offsets, buf);
    fft_z_kernel<<<120*10, 256, 0, stream>>>(buf, C1);
    fft_y_kernel<<<30*NKZ, 256, 0, stream>>>(C1, C2);
    fft_x_energy_kernel<<<NKZ*30, 256, 0, stream>>>(C2, box, acc);
    finalize_kernel<<<1, 1, 0, stream>>>(acc, box, (float*)d_out);
}